// Round 3
// baseline (200.867 us; speedup 1.0000x reference)
//
#include <hip/hip_runtime.h>
#include <hip/hip_bf16.h>
#include <stdint.h>

#define D_MODEL 1024
#define NH 16
#define DK 64
#define BB 2
#define SS 2048
#define MROWS (BB*SS)  // 4096

typedef __attribute__((ext_vector_type(8))) short bf16x8;
typedef __attribute__((ext_vector_type(4))) float f32x4;

__device__ __forceinline__ short to_bf16(float f) {
  __hip_bfloat16 h = __float2bfloat16(f);
  union { __hip_bfloat16 b; short s; } u; u.b = h; return u.s;
}

__device__ __forceinline__ f32x4 mfma16(bf16x8 a, bf16x8 b, f32x4 c) {
  return __builtin_amdgcn_mfma_f32_16x16x32_bf16(a, b, c, 0, 0, 0);
}

__device__ __forceinline__ void gload_lds16(const void* g, void* l) {
  __builtin_amdgcn_global_load_lds(
      (const __attribute__((address_space(1))) unsigned int*)g,
      (__attribute__((address_space(3))) unsigned int*)l,
      16, 0, 0);
}

// ---------------- batched f32 -> bf16 converts ----------------
__global__ __launch_bounds__(256) void cvt3(const float* __restrict__ a,
                                            const float* __restrict__ b,
                                            const float* __restrict__ c,
                                            short* __restrict__ oa,
                                            short* __restrict__ ob,
                                            short* __restrict__ oc) {
  const int z = blockIdx.z;
  const float* x = z == 0 ? a : z == 1 ? b : c;
  short* y = z == 0 ? oa : z == 1 ? ob : oc;
  const int i = (blockIdx.x * 256 + threadIdx.x) * 4;
  const float4 v = *(const float4*)(x + i);
  short4 o;
  o.x = to_bf16(v.x); o.y = to_bf16(v.y); o.z = to_bf16(v.z); o.w = to_bf16(v.w);
  *(short4*)(y + i) = o;
}

__global__ __launch_bounds__(256) void cvt4(const float* __restrict__ a,
                                            const float* __restrict__ b,
                                            const float* __restrict__ c,
                                            const float* __restrict__ d,
                                            short* __restrict__ oa,
                                            short* __restrict__ ob,
                                            short* __restrict__ oc,
                                            short* __restrict__ od) {
  const int z = blockIdx.z;
  const float* x = z == 0 ? a : z == 1 ? b : z == 2 ? c : d;
  short* y = z == 0 ? oa : z == 1 ? ob : z == 2 ? oc : od;
  const int i = (blockIdx.x * 256 + threadIdx.x) * 4;
  const float4 v = *(const float4*)(x + i);
  short4 o;
  o.x = to_bf16(v.x); o.y = to_bf16(v.y); o.z = to_bf16(v.z); o.w = to_bf16(v.w);
  *(short4*)(y + i) = o;
}

// ---------------- batched QKV projection: Y = X * W^T + b ----------------
// z=0: Q -> (b,h,s,dk) scaled by 1/8;  z=1: K -> (b,h,s,dk);  z=2: V -> (b,h,dk,s)
__global__ __launch_bounds__(256) void gemm_qkv(const short* __restrict__ Xq,
                                                const short* __restrict__ Xk,
                                                const short* __restrict__ Xv,
                                                const short* __restrict__ Wq,
                                                const short* __restrict__ Wk,
                                                const short* __restrict__ Wv,
                                                const float* __restrict__ bq,
                                                const float* __restrict__ bk,
                                                const float* __restrict__ bv,
                                                short* __restrict__ Qh,
                                                short* __restrict__ Kh,
                                                short* __restrict__ VT) {
  constexpr int K = 1024;
  __shared__ short As[128 * 32];
  __shared__ short Bs[128 * 32];
  const int z = blockIdx.z;
  const short* A    = z == 0 ? Xq : z == 1 ? Xk : Xv;
  const short* Wt   = z == 0 ? Wq : z == 1 ? Wk : Wv;
  const float* bias = z == 0 ? bq : z == 1 ? bk : bv;

  const int tid = threadIdx.x;
  const int w = tid >> 6, lane = tid & 63;
  const int m0 = blockIdx.x * 128, n0 = blockIdx.y * 128;
  const int wm = w >> 1, wn = w & 1;
  const int fr = lane & 15, fg = lane >> 4;
  const int srow = tid >> 2, scol = (tid & 3) * 8;

  f32x4 acc[4][4] = {};

  for (int k0 = 0; k0 < K; k0 += 32) {
    __syncthreads();
#pragma unroll
    for (int i = 0; i < 2; ++i) {
      const int row = i * 64 + srow;
      gload_lds16(A  + (size_t)(m0 + row) * K + k0 + scol, As + row * 32 + scol);
      gload_lds16(Wt + (size_t)(n0 + row) * K + k0 + scol, Bs + row * 32 + scol);
    }
    asm volatile("s_waitcnt vmcnt(0)" ::: "memory");
    __syncthreads();

    bf16x8 af[4], bfr[4];
#pragma unroll
    for (int i = 0; i < 4; ++i) {
      af[i]  = *(const bf16x8*)(As + (wm * 64 + i * 16 + fr) * 32 + fg * 8);
      bfr[i] = *(const bf16x8*)(Bs + (wn * 64 + i * 16 + fr) * 32 + fg * 8);
    }
    __builtin_amdgcn_s_setprio(1);
#pragma unroll
    for (int mi = 0; mi < 4; ++mi)
#pragma unroll
      for (int ni = 0; ni < 4; ++ni)
        acc[mi][ni] = mfma16(af[mi], bfr[ni], acc[mi][ni]);
    __builtin_amdgcn_s_setprio(0);
  }

  const float scale = (z == 0) ? 0.125f : 1.0f;
#pragma unroll
  for (int mi = 0; mi < 4; ++mi)
#pragma unroll
    for (int ni = 0; ni < 4; ++ni) {
      const int col = n0 + wn * 64 + ni * 16 + fr;
      const float bval = bias[col];
      const int h = col >> 6, d = col & 63;
#pragma unroll
      for (int r = 0; r < 4; ++r) {
        const int row = m0 + wm * 64 + mi * 16 + fg * 4 + r;
        const float val = (acc[mi][ni][r] + bval) * scale;
        const int b = row >> 11, s = row & (SS - 1);
        if (z < 2) {
          short* dst = (z == 0) ? Qh : Kh;
          dst[((size_t)(b * NH + h) * SS + s) * DK + d] = to_bf16(val);
        } else {
          VT[((size_t)(b * NH + h) * DK + d) * SS + s] = to_bf16(val);
        }
      }
    }
}

// ---------------- O-projection: 128x64 tiles, f32 out ----------------
__global__ __launch_bounds__(256) void gemm_out(const short* __restrict__ A,
                                                const short* __restrict__ Wt,
                                                const float* __restrict__ bias,
                                                float* __restrict__ Y) {
  constexpr int K = 1024;
  __shared__ short As[128 * 32];
  __shared__ short Bs[64 * 32];
  const int tid = threadIdx.x;
  const int w = tid >> 6, lane = tid & 63;
  const int m0 = blockIdx.x * 128, n0 = blockIdx.y * 64;
  const int wm = w >> 1, wn = w & 1;
  const int fr = lane & 15, fg = lane >> 4;
  const int srow = tid >> 2, scol = (tid & 3) * 8;

  f32x4 acc[4][2] = {};

  for (int k0 = 0; k0 < K; k0 += 32) {
    __syncthreads();
#pragma unroll
    for (int i = 0; i < 2; ++i) {
      const int row = i * 64 + srow;
      gload_lds16(A + (size_t)(m0 + row) * K + k0 + scol, As + row * 32 + scol);
    }
    gload_lds16(Wt + (size_t)(n0 + srow) * K + k0 + scol, Bs + srow * 32 + scol);
    asm volatile("s_waitcnt vmcnt(0)" ::: "memory");
    __syncthreads();

    bf16x8 af[4], bfr[2];
#pragma unroll
    for (int i = 0; i < 4; ++i)
      af[i] = *(const bf16x8*)(As + (wm * 64 + i * 16 + fr) * 32 + fg * 8);
#pragma unroll
    for (int i = 0; i < 2; ++i)
      bfr[i] = *(const bf16x8*)(Bs + (wn * 32 + i * 16 + fr) * 32 + fg * 8);
    __builtin_amdgcn_s_setprio(1);
#pragma unroll
    for (int mi = 0; mi < 4; ++mi)
#pragma unroll
      for (int ni = 0; ni < 2; ++ni)
        acc[mi][ni] = mfma16(af[mi], bfr[ni], acc[mi][ni]);
    __builtin_amdgcn_s_setprio(0);
  }

#pragma unroll
  for (int mi = 0; mi < 4; ++mi)
#pragma unroll
    for (int ni = 0; ni < 2; ++ni) {
      const int col = n0 + wn * 32 + ni * 16 + fr;
      const float bval = bias[col];
#pragma unroll
      for (int r = 0; r < 4; ++r) {
        const int row = m0 + wm * 64 + mi * 16 + fg * 4 + r;
        Y[(size_t)row * D_MODEL + col] = acc[mi][ni][r] + bval;
      }
    }
}

// ---------------- causal flash attention ----------------
// 16 q-rows per wave, KVBLK=64, 1024 blocks (4/CU). Swapped QK^T: lane holds
// S[k = kt*16 + fg*4 + r][q = fr]; softmax over k in-register + 2 shfl.
// V loads hoisted before softmax; defer-max rescale (THR=8).
__global__ __launch_bounds__(256, 4) void attn_kernel(const short* __restrict__ Qh,
                                                      const short* __restrict__ Kh,
                                                      const short* __restrict__ VT,
                                                      short* __restrict__ AO) {
  __shared__ short P_lds[4][16 * 64];  // 8 KB
  const int tid = threadIdx.x, w = tid >> 6, lane = tid & 63;
  const int fr = lane & 15, fg = lane >> 4;
  const int kr = fg * 4;

  // XCD swizzle: 1024 blocks, 128 consecutive logical ids per XCD
  const int bid = blockIdx.x;
  const int lid = ((bid & 7) << 7) | (bid >> 3);
  const int bh = lid >> 5;      // 0..31
  const int xq = lid & 31;      // 0..31
  const int b = bh >> 4, h = bh & 15;

  // balanced strips {x, 127-x, 32+x, 95-x}: exactly 66 tiles per block
  const int strip = (w == 0) ? xq : (w == 1) ? (127 - xq) : (w == 2) ? (32 + xq) : (95 - xq);
  const int q0 = strip * 16;

  const short* Qp = Qh + (size_t)bh * SS * DK;
  const short* Kp = Kh + (size_t)bh * SS * DK;
  const short* Vp = VT + (size_t)bh * DK * SS;

  bf16x8 qf[2];
#pragma unroll
  for (int hh = 0; hh < 2; ++hh)
    qf[hh] = *(const bf16x8*)(Qp + (size_t)(q0 + fr) * DK + hh * 32 + fg * 8);

  f32x4 o[4] = {};  // lane holds O^T[d = t*16+fg*4+r][q = fr]
  float m_run = -1e30f, l_run = 0.f;

  const int nfull = q0 >> 6;
  const int swz = (fr & 7) << 4;
  short* pw = P_lds[w];

  for (int ti = 0; ti <= nfull; ++ti) {
    const int k0 = ti * 64;

    bf16x8 kf[4][2];
#pragma unroll
    for (int kt = 0; kt < 4; ++kt)
#pragma unroll
      for (int hh = 0; hh < 2; ++hh)
        kf[kt][hh] = *(const bf16x8*)(Kp + (size_t)(k0 + kt * 16 + fr) * DK + hh * 32 + fg * 8);

    f32x4 st[4] = {};
    __builtin_amdgcn_s_setprio(1);
#pragma unroll
    for (int kt = 0; kt < 4; ++kt) {
      st[kt] = mfma16(kf[kt][0], qf[0], st[kt]);
      st[kt] = mfma16(kf[kt][1], qf[1], st[kt]);
    }
    __builtin_amdgcn_s_setprio(0);

    // V loads issued early: latency hides under softmax
    bf16x8 vf[2][4];
#pragma unroll
    for (int c = 0; c < 2; ++c)
#pragma unroll
      for (int t = 0; t < 4; ++t)
        vf[c][t] = *(const bf16x8*)(Vp + (size_t)(t * 16 + fr) * SS + k0 + c * 32 + fg * 8);

    if (ti == nfull) {
#pragma unroll
      for (int kt = 0; kt < 4; ++kt)
#pragma unroll
        for (int r = 0; r < 4; ++r)
          if (k0 + kt * 16 + kr + r > q0 + fr) st[kt][r] = -1e30f;
    }

    float pmax = st[0][0];
#pragma unroll
    for (int kt = 0; kt < 4; ++kt)
#pragma unroll
      for (int r = 0; r < 4; ++r) pmax = fmaxf(pmax, st[kt][r]);
    pmax = fmaxf(pmax, __shfl_xor(pmax, 16));
    pmax = fmaxf(pmax, __shfl_xor(pmax, 32));

    if (!__all(pmax <= m_run + 8.0f)) {
      const float mn = fmaxf(m_run, pmax);
      const float al = __expf(m_run - mn);
      m_run = mn;
      l_run *= al;
#pragma unroll
      for (int t = 0; t < 4; ++t)
#pragma unroll
        for (int r = 0; r < 4; ++r) o[t][r] *= al;
    }

    float ps = 0.f;
    short pb[4][4];
#pragma unroll
    for (int kt = 0; kt < 4; ++kt)
#pragma unroll
      for (int r = 0; r < 4; ++r) {
        const float p = __expf(st[kt][r] - m_run);
        ps += p;
        pb[kt][r] = to_bf16(p);
      }
    ps += __shfl_xor(ps, 16);
    ps += __shfl_xor(ps, 32);
    l_run += ps;

    char* base = (char*)pw;
#pragma unroll
    for (int kt = 0; kt < 4; ++kt) {
      short4 sv = {pb[kt][0], pb[kt][1], pb[kt][2], pb[kt][3]};
      *(short4*)(base + ((fr * 128 + kt * 32 + fg * 8) ^ swz)) = sv;
    }
    asm volatile("s_waitcnt lgkmcnt(0)" ::: "memory");
    bf16x8 pf[2];
#pragma unroll
    for (int c = 0; c < 2; ++c)
      pf[c] = *(const bf16x8*)(base + ((fr * 128 + c * 64 + fg * 16) ^ swz));

    __builtin_amdgcn_s_setprio(1);
#pragma unroll
    for (int c = 0; c < 2; ++c)
#pragma unroll
      for (int t = 0; t < 4; ++t)
        o[t] = mfma16(vf[c][t], pf[c], o[t]);
    __builtin_amdgcn_s_setprio(0);
  }

  const float inv = 1.0f / l_run;
  const int s = q0 + fr;
#pragma unroll
  for (int t = 0; t < 4; ++t) {
    short4 ov = {to_bf16(o[t][0] * inv), to_bf16(o[t][1] * inv),
                 to_bf16(o[t][2] * inv), to_bf16(o[t][3] * inv)};
    *(short4*)(AO + (size_t)(b * SS + s) * D_MODEL + h * 64 + t * 16 + kr) = ov;
  }
}

extern "C" void kernel_launch(void* const* d_in, const int* in_sizes, int n_in,
                              void* d_out, int out_size, void* d_ws, size_t ws_size,
                              hipStream_t stream) {
  const float* q  = (const float*)d_in[0];
  const float* k  = (const float*)d_in[1];
  const float* v  = (const float*)d_in[2];
  const float* Wq = (const float*)d_in[4];
  const float* bq = (const float*)d_in[5];
  const float* Wk = (const float*)d_in[6];
  const float* bk = (const float*)d_in[7];
  const float* Wv = (const float*)d_in[8];
  const float* bv = (const float*)d_in[9];
  const float* Wo = (const float*)d_in[10];
  const float* bo = (const float*)d_in[11];

  char* ws = (char*)d_ws;
  const size_t MB = 1u << 20;
  short* Xq = (short*)(ws + 0 * MB);
  short* Xk = (short*)(ws + 8 * MB);
  short* Xv = (short*)(ws + 16 * MB);
  short* Bq = (short*)(ws + 24 * MB);
  short* Bk = (short*)(ws + 26 * MB);
  short* Bv = (short*)(ws + 28 * MB);
  short* Bo = (short*)(ws + 30 * MB);
  short* Qh = (short*)(ws + 32 * MB);
  short* Kh = (short*)(ws + 40 * MB);
  short* VT = (short*)(ws + 48 * MB);
  short* AO = (short*)(ws + 56 * MB);

  cvt3<<<dim3(MROWS * D_MODEL / 1024, 1, 3), 256, 0, stream>>>(q, k, v, Xq, Xk, Xv);
  cvt4<<<dim3(D_MODEL * D_MODEL / 1024, 1, 4), 256, 0, stream>>>(Wq, Wk, Wv, Wo, Bq, Bk, Bv, Bo);

  gemm_qkv<<<dim3(MROWS / 128, D_MODEL / 128, 3), 256, 0, stream>>>(
      Xq, Xk, Xv, Bq, Bk, Bv, bq, bk, bv, Qh, Kh, VT);

  attn_kernel<<<dim3(1024), 256, 0, stream>>>(Qh, Kh, VT, AO);

  gemm_out<<<dim3(MROWS / 128, D_MODEL / 64), 256, 0, stream>>>(AO, Bo, bo, (float*)d_out);
}

// Round 4
// 144.444 us; speedup vs baseline: 1.3906x; 1.3906x over previous
//
#include <hip/hip_runtime.h>
#include <hip/hip_bf16.h>
#include <stdint.h>

#define D_MODEL 1024
#define NH 16
#define DK 64
#define BB 2
#define SS 2048
#define MROWS (BB*SS)  // 4096

typedef __attribute__((ext_vector_type(8))) short bf16x8;
typedef __attribute__((ext_vector_type(4))) float f32x4;

__device__ __forceinline__ short to_bf16(float f) {
  __hip_bfloat16 h = __float2bfloat16(f);
  union { __hip_bfloat16 b; short s; } u; u.b = h; return u.s;
}

__device__ __forceinline__ f32x4 mfma16(bf16x8 a, bf16x8 b, f32x4 c) {
  return __builtin_amdgcn_mfma_f32_16x16x32_bf16(a, b, c, 0, 0, 0);
}

__device__ __forceinline__ void gload_lds16(const void* g, void* l) {
  __builtin_amdgcn_global_load_lds(
      (const __attribute__((address_space(1))) unsigned int*)g,
      (__attribute__((address_space(3))) unsigned int*)l,
      16, 0, 0);
}

// ---------------- batched f32 -> bf16 converts ----------------
__global__ __launch_bounds__(256) void cvt3(const float* __restrict__ a,
                                            const float* __restrict__ b,
                                            const float* __restrict__ c,
                                            short* __restrict__ oa,
                                            short* __restrict__ ob,
                                            short* __restrict__ oc) {
  const int z = blockIdx.z;
  const float* x = z == 0 ? a : z == 1 ? b : c;
  short* y = z == 0 ? oa : z == 1 ? ob : oc;
  const int i = (blockIdx.x * 256 + threadIdx.x) * 4;
  const float4 v = *(const float4*)(x + i);
  short4 o;
  o.x = to_bf16(v.x); o.y = to_bf16(v.y); o.z = to_bf16(v.z); o.w = to_bf16(v.w);
  *(short4*)(y + i) = o;
}

__global__ __launch_bounds__(256) void cvt4(const float* __restrict__ a,
                                            const float* __restrict__ b,
                                            const float* __restrict__ c,
                                            const float* __restrict__ d,
                                            short* __restrict__ oa,
                                            short* __restrict__ ob,
                                            short* __restrict__ oc,
                                            short* __restrict__ od) {
  const int z = blockIdx.z;
  const float* x = z == 0 ? a : z == 1 ? b : z == 2 ? c : d;
  short* y = z == 0 ? oa : z == 1 ? ob : z == 2 ? oc : od;
  const int i = (blockIdx.x * 256 + threadIdx.x) * 4;
  const float4 v = *(const float4*)(x + i);
  short4 o;
  o.x = to_bf16(v.x); o.y = to_bf16(v.y); o.z = to_bf16(v.z); o.w = to_bf16(v.w);
  *(short4*)(y + i) = o;
}

// ---------------- batched QKV projection: Y = X * W^T + b, BK=64 ----------
// z=0: Q -> (b,h,s,dk) scaled by 0.125*log2(e);  z=1: K -> (b,h,s,dk);
// z=2: V -> (b,h,dk,s)
__global__ __launch_bounds__(256) void gemm_qkv(const short* __restrict__ Xq,
                                                const short* __restrict__ Xk,
                                                const short* __restrict__ Xv,
                                                const short* __restrict__ Wq,
                                                const short* __restrict__ Wk,
                                                const short* __restrict__ Wv,
                                                const float* __restrict__ bq,
                                                const float* __restrict__ bk,
                                                const float* __restrict__ bv,
                                                short* __restrict__ Qh,
                                                short* __restrict__ Kh,
                                                short* __restrict__ VT) {
  constexpr int K = 1024;
  __shared__ short As[128 * 64];
  __shared__ short Bs[128 * 64];
  const int z = blockIdx.z;
  const short* A    = z == 0 ? Xq : z == 1 ? Xk : Xv;
  const short* Wt   = z == 0 ? Wq : z == 1 ? Wk : Wv;
  const float* bias = z == 0 ? bq : z == 1 ? bk : bv;

  const int tid = threadIdx.x;
  const int w = tid >> 6, lane = tid & 63;
  const int m0 = blockIdx.x * 128, n0 = blockIdx.y * 128;
  const int wm = w >> 1, wn = w & 1;
  const int fr = lane & 15, fg = lane >> 4;
  const int srow = tid >> 3, scol = (tid & 7) * 8;

  f32x4 acc[4][4] = {};

  for (int k0 = 0; k0 < K; k0 += 64) {
    __syncthreads();
#pragma unroll
    for (int i = 0; i < 4; ++i) {
      const int row = i * 32 + srow;
      gload_lds16(A  + (size_t)(m0 + row) * K + k0 + scol, As + row * 64 + scol);
      gload_lds16(Wt + (size_t)(n0 + row) * K + k0 + scol, Bs + row * 64 + scol);
    }
    asm volatile("s_waitcnt vmcnt(0)" ::: "memory");
    __syncthreads();

    bf16x8 af[4][2], bfr[4][2];
#pragma unroll
    for (int i = 0; i < 4; ++i)
#pragma unroll
      for (int hh = 0; hh < 2; ++hh) {
        af[i][hh]  = *(const bf16x8*)(As + (wm * 64 + i * 16 + fr) * 64 + hh * 32 + fg * 8);
        bfr[i][hh] = *(const bf16x8*)(Bs + (wn * 64 + i * 16 + fr) * 64 + hh * 32 + fg * 8);
      }
    __builtin_amdgcn_s_setprio(1);
#pragma unroll
    for (int mi = 0; mi < 4; ++mi)
#pragma unroll
      for (int ni = 0; ni < 4; ++ni) {
        acc[mi][ni] = mfma16(af[mi][0], bfr[ni][0], acc[mi][ni]);
        acc[mi][ni] = mfma16(af[mi][1], bfr[ni][1], acc[mi][ni]);
      }
    __builtin_amdgcn_s_setprio(0);
  }

  const float scale = (z == 0) ? 0.18033688011112042f : 1.0f;  // 0.125*log2(e)
#pragma unroll
  for (int mi = 0; mi < 4; ++mi)
#pragma unroll
    for (int ni = 0; ni < 4; ++ni) {
      const int col = n0 + wn * 64 + ni * 16 + fr;
      const float bval = bias[col];
      const int h = col >> 6, d = col & 63;
#pragma unroll
      for (int r = 0; r < 4; ++r) {
        const int row = m0 + wm * 64 + mi * 16 + fg * 4 + r;
        const float val = (acc[mi][ni][r] + bval) * scale;
        const int b = row >> 11, s = row & (SS - 1);
        if (z < 2) {
          short* dst = (z == 0) ? Qh : Kh;
          dst[((size_t)(b * NH + h) * SS + s) * DK + d] = to_bf16(val);
        } else {
          VT[((size_t)(b * NH + h) * DK + d) * SS + s] = to_bf16(val);
        }
      }
    }
}

// ---------------- O-projection: 128x64 tiles, BK=64, f32 out ----------------
__global__ __launch_bounds__(256) void gemm_out(const short* __restrict__ A,
                                                const short* __restrict__ Wt,
                                                const float* __restrict__ bias,
                                                float* __restrict__ Y) {
  constexpr int K = 1024;
  __shared__ short As[128 * 64];
  __shared__ short Bs[64 * 64];
  const int tid = threadIdx.x;
  const int w = tid >> 6, lane = tid & 63;
  const int m0 = blockIdx.x * 128, n0 = blockIdx.y * 64;
  const int wm = w >> 1, wn = w & 1;
  const int fr = lane & 15, fg = lane >> 4;
  const int srow = tid >> 3, scol = (tid & 7) * 8;

  f32x4 acc[4][2] = {};

  for (int k0 = 0; k0 < K; k0 += 64) {
    __syncthreads();
#pragma unroll
    for (int i = 0; i < 4; ++i) {
      const int row = i * 32 + srow;
      gload_lds16(A + (size_t)(m0 + row) * K + k0 + scol, As + row * 64 + scol);
    }
#pragma unroll
    for (int i = 0; i < 2; ++i) {
      const int row = i * 32 + srow;
      gload_lds16(Wt + (size_t)(n0 + row) * K + k0 + scol, Bs + row * 64 + scol);
    }
    asm volatile("s_waitcnt vmcnt(0)" ::: "memory");
    __syncthreads();

    bf16x8 af[4][2], bfr[2][2];
#pragma unroll
    for (int i = 0; i < 4; ++i)
#pragma unroll
      for (int hh = 0; hh < 2; ++hh)
        af[i][hh] = *(const bf16x8*)(As + (wm * 64 + i * 16 + fr) * 64 + hh * 32 + fg * 8);
#pragma unroll
    for (int i = 0; i < 2; ++i)
#pragma unroll
      for (int hh = 0; hh < 2; ++hh)
        bfr[i][hh] = *(const bf16x8*)(Bs + (wn * 32 + i * 16 + fr) * 64 + hh * 32 + fg * 8);
    __builtin_amdgcn_s_setprio(1);
#pragma unroll
    for (int mi = 0; mi < 4; ++mi)
#pragma unroll
      for (int ni = 0; ni < 2; ++ni) {
        acc[mi][ni] = mfma16(af[mi][0], bfr[ni][0], acc[mi][ni]);
        acc[mi][ni] = mfma16(af[mi][1], bfr[ni][1], acc[mi][ni]);
      }
    __builtin_amdgcn_s_setprio(0);
  }

#pragma unroll
  for (int mi = 0; mi < 4; ++mi)
#pragma unroll
    for (int ni = 0; ni < 2; ++ni) {
      const int col = n0 + wn * 32 + ni * 16 + fr;
      const float bval = bias[col];
#pragma unroll
      for (int r = 0; r < 4; ++r) {
        const int row = m0 + wm * 64 + mi * 16 + fg * 4 + r;
        Y[(size_t)row * D_MODEL + col] = acc[mi][ni][r] + bval;
      }
    }
}

// ---------------- causal flash attention ----------------
// 32 q-rows/wave, KVBLK=64, 512 blocks. Swapped QK^T (lane holds
// S^T[k=kt*16+fg*4+r][q=fr]); exp2 softmax (Q pre-scaled by 0.125*log2e);
// K prefetched one tile ahead; V issued before the LDS fence; l accumulated
// via a ones-row MFMA tile (o[4]); defer-max rescale (THR=11 in log2 units).
__global__ __launch_bounds__(256, 2) void attn_kernel(const short* __restrict__ Qh,
                                                      const short* __restrict__ Kh,
                                                      const short* __restrict__ VT,
                                                      short* __restrict__ AO) {
  __shared__ short P_lds[4][2][16 * 64];  // 16 KB
  const int tid = threadIdx.x, w = tid >> 6, lane = tid & 63;
  const int fr = lane & 15, fg = lane >> 4;
  const int kr = fg * 4;

  // XCD swizzle: 512 blocks, 64 consecutive logical ids per XCD
  const int bid = blockIdx.x;
  const int lid = ((bid & 7) << 6) | (bid >> 3);
  const int bh = lid >> 4;      // 0..31
  const int xq = lid & 15;      // 0..15
  const int b = bh >> 4, h = bh & 15;

  // balanced strips {x, 31-x, 32+x, 63-x}: constant work per block
  const int strip = (w == 0) ? xq : (w == 1) ? (31 - xq) : (w == 2) ? (32 + xq) : (63 - xq);
  const int q0w = strip * 32;

  const short* Qp = Qh + (size_t)bh * SS * DK;
  const short* Kp = Kh + (size_t)bh * SS * DK;
  const short* Vp = VT + (size_t)bh * DK * SS;

  bf16x8 qf[2][2];
#pragma unroll
  for (int qt = 0; qt < 2; ++qt)
#pragma unroll
    for (int hh = 0; hh < 2; ++hh)
      qf[qt][hh] = *(const bf16x8*)(Qp + (size_t)(q0w + qt * 16 + fr) * DK + hh * 32 + fg * 8);

  // ones A-fragment (row 0 of the l-sum tile = 1.0, rest 0)
  const short onev = (fr == 0) ? (short)0x3F80 : (short)0;
  const bf16x8 af4 = {onev, onev, onev, onev, onev, onev, onev, onev};

  f32x4 o[5][2] = {};  // [d-tile 0..3, 4 = l-sum][qt]
  float m_run[2] = {-1e30f, -1e30f};

  const int nfull = q0w >> 6;
  const int swz = (fr & 7) << 4;

  bf16x8 kf[4][2];
#pragma unroll
  for (int kt = 0; kt < 4; ++kt)
#pragma unroll
    for (int hh = 0; hh < 2; ++hh)
      kf[kt][hh] = *(const bf16x8*)(Kp + (size_t)(kt * 16 + fr) * DK + hh * 32 + fg * 8);

  for (int ti = 0; ti <= nfull; ++ti) {
    const int k0 = ti * 64;
    const bool hasNext = ti < nfull;

    // prefetch next K tile (latency hides under QK + softmax)
    bf16x8 kn[4][2];
    if (hasNext) {
#pragma unroll
      for (int kt = 0; kt < 4; ++kt)
#pragma unroll
        for (int hh = 0; hh < 2; ++hh)
          kn[kt][hh] = *(const bf16x8*)(Kp + (size_t)(k0 + 64 + kt * 16 + fr) * DK + hh * 32 + fg * 8);
    }

    f32x4 st[4][2] = {};
    __builtin_amdgcn_s_setprio(1);
#pragma unroll
    for (int kt = 0; kt < 4; ++kt)
#pragma unroll
      for (int qt = 0; qt < 2; ++qt) {
        st[kt][qt] = mfma16(kf[kt][0], qf[qt][0], st[kt][qt]);
        st[kt][qt] = mfma16(kf[kt][1], qf[qt][1], st[kt][qt]);
      }
    __builtin_amdgcn_s_setprio(0);

    // V loads issued before the LDS fence: latency hides under softmax
    bf16x8 vf[2][4];
#pragma unroll
    for (int c = 0; c < 2; ++c)
#pragma unroll
      for (int t = 0; t < 4; ++t)
        vf[c][t] = *(const bf16x8*)(Vp + (size_t)(t * 16 + fr) * SS + k0 + c * 32 + fg * 8);

    if (ti == nfull) {
#pragma unroll
      for (int kt = 0; kt < 4; ++kt)
#pragma unroll
        for (int qt = 0; qt < 2; ++qt)
#pragma unroll
          for (int r = 0; r < 4; ++r)
            if (k0 + kt * 16 + kr + r > q0w + qt * 16 + fr) st[kt][qt][r] = -1e30f;
    }

    float pmax[2];
#pragma unroll
    for (int qt = 0; qt < 2; ++qt) {
      float mt = st[0][qt][0];
#pragma unroll
      for (int kt = 0; kt < 4; ++kt)
#pragma unroll
        for (int r = 0; r < 4; ++r) mt = fmaxf(mt, st[kt][qt][r]);
      mt = fmaxf(mt, __shfl_xor(mt, 16));
      mt = fmaxf(mt, __shfl_xor(mt, 32));
      pmax[qt] = mt;
    }

    const bool ok = (pmax[0] <= m_run[0] + 11.0f) && (pmax[1] <= m_run[1] + 11.0f);
    if (!__all(ok)) {
#pragma unroll
      for (int qt = 0; qt < 2; ++qt) {
        const float mn = fmaxf(m_run[qt], pmax[qt]);
        const float al = __builtin_amdgcn_exp2f(m_run[qt] - mn);
        m_run[qt] = mn;
#pragma unroll
        for (int t = 0; t < 5; ++t)
#pragma unroll
          for (int r = 0; r < 4; ++r) o[t][qt][r] *= al;
      }
    }

#pragma unroll
    for (int qt = 0; qt < 2; ++qt) {
      char* base = (char*)P_lds[w][qt];
#pragma unroll
      for (int kt = 0; kt < 4; ++kt) {
        short4 sv;
        sv.x = to_bf16(__builtin_amdgcn_exp2f(st[kt][qt][0] - m_run[qt]));
        sv.y = to_bf16(__builtin_amdgcn_exp2f(st[kt][qt][1] - m_run[qt]));
        sv.z = to_bf16(__builtin_amdgcn_exp2f(st[kt][qt][2] - m_run[qt]));
        sv.w = to_bf16(__builtin_amdgcn_exp2f(st[kt][qt][3] - m_run[qt]));
        *(short4*)(base + ((fr * 128 + kt * 32 + fg * 8) ^ swz)) = sv;
      }
    }
    asm volatile("s_waitcnt lgkmcnt(0)" ::: "memory");

    bf16x8 pf[2][2];
#pragma unroll
    for (int qt = 0; qt < 2; ++qt)
#pragma unroll
      for (int c = 0; c < 2; ++c)
        pf[qt][c] = *(const bf16x8*)((const char*)P_lds[w][qt] + ((fr * 128 + c * 64 + fg * 16) ^ swz));

    __builtin_amdgcn_s_setprio(1);
#pragma unroll
    for (int c = 0; c < 2; ++c)
#pragma unroll
      for (int qt = 0; qt < 2; ++qt) {
#pragma unroll
        for (int t = 0; t < 4; ++t)
          o[t][qt] = mfma16(vf[c][t], pf[qt][c], o[t][qt]);
        o[4][qt] = mfma16(af4, pf[qt][c], o[4][qt]);
      }
    __builtin_amdgcn_s_setprio(0);

    if (hasNext) {
#pragma unroll
      for (int kt = 0; kt < 4; ++kt)
#pragma unroll
        for (int hh = 0; hh < 2; ++hh) kf[kt][hh] = kn[kt][hh];
    }
  }

  // epilogue: l lives in o[4][qt][0] on lanes 0..15 (row 0); broadcast by shfl
#pragma unroll
  for (int qt = 0; qt < 2; ++qt) {
    const float l = __shfl(o[4][qt][0], fr);
    const float inv = 1.0f / l;
    const int s = q0w + qt * 16 + fr;
#pragma unroll
    for (int t = 0; t < 4; ++t) {
      short4 ov = {to_bf16(o[t][qt][0] * inv), to_bf16(o[t][qt][1] * inv),
                   to_bf16(o[t][qt][2] * inv), to_bf16(o[t][qt][3] * inv)};
      *(short4*)(AO + (size_t)(b * SS + s) * D_MODEL + h * 64 + t * 16 + kr) = ov;
    }
  }
}

extern "C" void kernel_launch(void* const* d_in, const int* in_sizes, int n_in,
                              void* d_out, int out_size, void* d_ws, size_t ws_size,
                              hipStream_t stream) {
  const float* q  = (const float*)d_in[0];
  const float* k  = (const float*)d_in[1];
  const float* v  = (const float*)d_in[2];
  const float* Wq = (const float*)d_in[4];
  const float* bq = (const float*)d_in[5];
  const float* Wk = (const float*)d_in[6];
  const float* bk = (const float*)d_in[7];
  const float* Wv = (const float*)d_in[8];
  const float* bv = (const float*)d_in[9];
  const float* Wo = (const float*)d_in[10];
  const float* bo = (const float*)d_in[11];

  char* ws = (char*)d_ws;
  const size_t MB = 1u << 20;
  short* Xq = (short*)(ws + 0 * MB);
  short* Xk = (short*)(ws + 8 * MB);
  short* Xv = (short*)(ws + 16 * MB);
  short* Bq = (short*)(ws + 24 * MB);
  short* Bk = (short*)(ws + 26 * MB);
  short* Bv = (short*)(ws + 28 * MB);
  short* Bo = (short*)(ws + 30 * MB);
  short* Qh = (short*)(ws + 32 * MB);
  short* Kh = (short*)(ws + 40 * MB);
  short* VT = (short*)(ws + 48 * MB);
  short* AO = (short*)(ws + 56 * MB);

  cvt3<<<dim3(MROWS * D_MODEL / 1024, 1, 3), 256, 0, stream>>>(q, k, v, Xq, Xk, Xv);
  cvt4<<<dim3(D_MODEL * D_MODEL / 1024, 1, 4), 256, 0, stream>>>(Wq, Wk, Wv, Wo, Bq, Bk, Bv, Bo);

  gemm_qkv<<<dim3(MROWS / 128, D_MODEL / 128, 3), 256, 0, stream>>>(
      Xq, Xk, Xv, Bq, Bk, Bv, bq, bk, bv, Qh, Kh, VT);

  attn_kernel<<<dim3(512), 256, 0, stream>>>(Qh, Kh, VT, AO);

  gemm_out<<<dim3(MROWS / 128, D_MODEL / 64), 256, 0, stream>>>(AO, Bo, bo, (float*)d_out);
}